// Round 2
// baseline (444.866 us; speedup 1.0000x reference)
//
#include <hip/hip_runtime.h>

// SelfAttention (SAGAN-style), MI355X gfx950.
// Pipeline: proj (f16 MFMA GEMM for f,g,h) -> flash attention (j-split x2,
// unnormalized partials + m,l stats) -> combine (normalize + transpose).
//
// ws layout (needs ~64.5 MB):
//   qw  f16 [4][4096][256]   8 MB   (Q = f^T, row-major in k)
//   kw  f16 [4][4096][256]   8 MB   (K = g^T)
//   vw  f16 [4][512][4096]  16 MB   (V = h, row-major in n)
//   op  f16 [2][4][4096][512] 32 MB (unnormalized O partials per j-half)
//   st  f32 [2][4][4096][2]  0.5 MB (m, l per row per j-half)

#define NPIX 4096
#define CIN  512

typedef _Float16 f16x4 __attribute__((ext_vector_type(4)));
typedef _Float16 f16x8 __attribute__((ext_vector_type(8)));
typedef float    f32x4 __attribute__((ext_vector_type(4)));

#define MFMA16(a, b, c) __builtin_amdgcn_mfma_f32_16x16x16f16(a, b, c, 0, 0, 0)

// ---------------------------------------------------------------------------
// Projection: out[o][n] = sum_c W[o][c] * x[b][c][n] + bias[o], o in [0,1024)
// o<256 -> Q (f), 256..511 -> K (g), 512..1023 -> V (h).
// Tile 64(M) x 64(N), BK=32, 4 waves (2x2 quadrants of 32x32).
// ---------------------------------------------------------------------------
__global__ __launch_bounds__(256) void proj_kernel(
    const float* __restrict__ x,
    const float* __restrict__ f_w, const float* __restrict__ f_b,
    const float* __restrict__ g_w, const float* __restrict__ g_b,
    const float* __restrict__ h_w, const float* __restrict__ h_b,
    _Float16* __restrict__ qw, _Float16* __restrict__ kw,
    _Float16* __restrict__ vw)
{
    const int b  = blockIdx.z;
    const int n0 = blockIdx.x * 64;
    const int o0 = blockIdx.y * 64;

    const float* wsrc; const float* bsrc;
    if (o0 < 256)      { wsrc = f_w + (size_t)o0 * CIN;         bsrc = f_b + o0; }
    else if (o0 < 512) { wsrc = g_w + (size_t)(o0 - 256) * CIN; bsrc = g_b + (o0 - 256); }
    else               { wsrc = h_w + (size_t)(o0 - 512) * CIN; bsrc = h_b + (o0 - 512); }

    // +8 f16 pad -> 80B rows: keeps 16B alignment, 2-way-max bank aliasing
    __shared__ _Float16 Wt[64][40];  // [m][k]
    __shared__ _Float16 Xt[64][40];  // [n][k] (transposed x tile)

    const int t = threadIdx.x;
    const int lane = t & 63, wv = t >> 6;
    const int wm = wv >> 1, wn = wv & 1;
    const int gi = lane >> 4, li = lane & 15;

    f32x4 acc[2][2];
    #pragma unroll
    for (int i = 0; i < 2; ++i)
        #pragma unroll
        for (int j = 0; j < 2; ++j) acc[i][j] = f32x4{0.f, 0.f, 0.f, 0.f};

    for (int kk = 0; kk < CIN; kk += 32) {
        {   // stage W tile 64x32 (fp32 -> f16)
            const int r = t >> 2, c8 = (t & 3) * 8;
            const float* p = wsrc + (size_t)r * CIN + kk + c8;
            const float4 v0 = *(const float4*)p;
            const float4 v1 = *(const float4*)(p + 4);
            _Float16* d = &Wt[r][c8];
            d[0] = (_Float16)v0.x; d[1] = (_Float16)v0.y;
            d[2] = (_Float16)v0.z; d[3] = (_Float16)v0.w;
            d[4] = (_Float16)v1.x; d[5] = (_Float16)v1.y;
            d[6] = (_Float16)v1.z; d[7] = (_Float16)v1.w;
        }
        {   // stage X tile 32(c)x64(n), transposed into Xt[n][c]
            const int c = t >> 3, n8 = (t & 7) * 8;
            const float* p = x + ((size_t)b * CIN + kk + c) * NPIX + n0 + n8;
            const float4 v0 = *(const float4*)p;
            const float4 v1 = *(const float4*)(p + 4);
            Xt[n8 + 0][c] = (_Float16)v0.x; Xt[n8 + 1][c] = (_Float16)v0.y;
            Xt[n8 + 2][c] = (_Float16)v0.z; Xt[n8 + 3][c] = (_Float16)v0.w;
            Xt[n8 + 4][c] = (_Float16)v1.x; Xt[n8 + 5][c] = (_Float16)v1.y;
            Xt[n8 + 6][c] = (_Float16)v1.z; Xt[n8 + 7][c] = (_Float16)v1.w;
        }
        __syncthreads();
        #pragma unroll
        for (int kh = 0; kh < 2; ++kh) {
            const int ko = kh * 16 + gi * 4;
            f16x4 a0 = *(const f16x4*)&Wt[wm * 32 +      li][ko];
            f16x4 a1 = *(const f16x4*)&Wt[wm * 32 + 16 + li][ko];
            f16x4 b0 = *(const f16x4*)&Xt[wn * 32 +      li][ko];
            f16x4 b1 = *(const f16x4*)&Xt[wn * 32 + 16 + li][ko];
            acc[0][0] = MFMA16(a0, b0, acc[0][0]);
            acc[0][1] = MFMA16(a0, b1, acc[0][1]);
            acc[1][0] = MFMA16(a1, b0, acc[1][0]);
            acc[1][1] = MFMA16(a1, b1, acc[1][1]);
        }
        __syncthreads();
    }

    #pragma unroll
    for (int mf = 0; mf < 2; ++mf)
        #pragma unroll
        for (int nf = 0; nf < 2; ++nf) {
            const int obase = o0 + wm * 32 + mf * 16 + gi * 4;  // o of reg r=0
            const int n     = n0 + wn * 32 + nf * 16 + li;
            const int brel  = wm * 32 + mf * 16 + gi * 4;
            float v[4];
            #pragma unroll
            for (int r = 0; r < 4; ++r) v[r] = acc[mf][nf][r] + bsrc[brel + r];
            if (o0 < 512) {
                _Float16* dst = (o0 < 256) ? qw : kw;
                const int kb  = (o0 < 256) ? obase : (obase - 256);
                f16x4 pk;
                pk[0] = (_Float16)v[0]; pk[1] = (_Float16)v[1];
                pk[2] = (_Float16)v[2]; pk[3] = (_Float16)v[3];
                *(f16x4*)&dst[((size_t)b * NPIX + n) * 256 + kb] = pk;
            } else {
                #pragma unroll
                for (int r = 0; r < 4; ++r)
                    vw[((size_t)b * CIN + (obase - 512 + r)) * NPIX + n] =
                        (_Float16)v[r];
            }
        }
}

// ---------------------------------------------------------------------------
// Flash attention over one j-half (2048 keys). 8 waves, each owns 16 Q rows
// (softmax fully wave-local). K/V tiles (BN=32) staged in LDS, shared by all.
// ---------------------------------------------------------------------------
__global__ __launch_bounds__(512, 2) void attn_kernel(
    const _Float16* __restrict__ qw, const _Float16* __restrict__ kw,
    const _Float16* __restrict__ vw,
    _Float16* __restrict__ opart, float* __restrict__ stats)
{
    const int b = blockIdx.z, jh = blockIdx.y, rb = blockIdx.x;
    const int t = threadIdx.x, lane = t & 63, wv = t >> 6;
    const int gi = lane >> 4, li = lane & 15;
    const int i0 = rb * 128 + wv * 16;

    __shared__ _Float16 Kt[32][264];    // [j][k], pad 256->264
    __shared__ _Float16 Vt[512][40];    // [c][j], pad 32->40
    __shared__ _Float16 Pt[8][16][40];  // per-wave P tile [i][j]

    // Q fragments in registers: A[i=li][k = ks*16 + gi*4 + e]
    f16x4 qf[16];
    {
        const _Float16* qb = qw + ((size_t)b * NPIX + i0 + li) * 256 + gi * 4;
        #pragma unroll
        for (int ks = 0; ks < 16; ++ks) qf[ks] = *(const f16x4*)(qb + ks * 16);
    }

    f32x4 oacc[32];
    #pragma unroll
    for (int i = 0; i < 32; ++i) oacc[i] = f32x4{0.f, 0.f, 0.f, 0.f};
    float m_run[4] = {-__builtin_inff(), -__builtin_inff(),
                      -__builtin_inff(), -__builtin_inff()};
    float l_run[4] = {0.f, 0.f, 0.f, 0.f};

    for (int it = 0; it < 64; ++it) {
        const int j0 = jh * 2048 + it * 32;
        {   // stage K tile [32][256]
            const int j = t >> 4, k16 = (t & 15) * 16;
            const _Float16* p = kw + ((size_t)b * NPIX + j0 + j) * 256 + k16;
            *(f16x8*)&Kt[j][k16]     = *(const f16x8*)p;
            *(f16x8*)&Kt[j][k16 + 8] = *(const f16x8*)(p + 8);
        }
        {   // stage V tile [512][32]
            const _Float16* p = vw + ((size_t)b * CIN + t) * NPIX + j0;
            *(f16x8*)&Vt[t][0]  = *(const f16x8*)(p);
            *(f16x8*)&Vt[t][8]  = *(const f16x8*)(p + 8);
            *(f16x8*)&Vt[t][16] = *(const f16x8*)(p + 16);
            *(f16x8*)&Vt[t][24] = *(const f16x8*)(p + 24);
        }
        __syncthreads();

        // S[i][j] = sum_k Q[i][k] K[j][k]  (two 16-col fragments)
        f32x4 s0 = f32x4{0.f, 0.f, 0.f, 0.f};
        f32x4 s1 = f32x4{0.f, 0.f, 0.f, 0.f};
        #pragma unroll
        for (int ks = 0; ks < 16; ++ks) {
            const int ko = ks * 16 + gi * 4;
            f16x4 k0 = *(const f16x4*)&Kt[li][ko];
            f16x4 k1 = *(const f16x4*)&Kt[16 + li][ko];
            s0 = MFMA16(qf[ks], k0, s0);
            s1 = MFMA16(qf[ks], k1, s1);
        }

        // online softmax; lane holds rows gi*4+r, cols li / 16+li
        float scale[4];
        #pragma unroll
        for (int r = 0; r < 4; ++r) {
            float tm = fmaxf(s0[r], s1[r]);
            tm = fmaxf(tm, __shfl_xor(tm, 1));
            tm = fmaxf(tm, __shfl_xor(tm, 2));
            tm = fmaxf(tm, __shfl_xor(tm, 4));
            tm = fmaxf(tm, __shfl_xor(tm, 8));
            const float mnew = fmaxf(m_run[r], tm);
            scale[r] = __expf(m_run[r] - mnew);  // first iter: exp(-inf)=0
            const float p0 = __expf(s0[r] - mnew);
            const float p1 = __expf(s1[r] - mnew);
            float rs = p0 + p1;
            rs += __shfl_xor(rs, 1);
            rs += __shfl_xor(rs, 2);
            rs += __shfl_xor(rs, 4);
            rs += __shfl_xor(rs, 8);
            l_run[r] = l_run[r] * scale[r] + rs;
            m_run[r] = mnew;
            Pt[wv][gi * 4 + r][li]      = (_Float16)p0;
            Pt[wv][gi * 4 + r][16 + li] = (_Float16)p1;
        }

        const bool need = (scale[0] < 1.f) | (scale[1] < 1.f) |
                          (scale[2] < 1.f) | (scale[3] < 1.f);
        if (__any((int)need)) {
            #pragma unroll
            for (int cf = 0; cf < 32; ++cf)
                #pragma unroll
                for (int r = 0; r < 4; ++r) oacc[cf][r] *= scale[r];
        }

        // PV: O[i][c] += P[i][j] * V[j][c]
        f16x4 pa0 = *(const f16x4*)&Pt[wv][li][gi * 4];
        f16x4 pa1 = *(const f16x4*)&Pt[wv][li][16 + gi * 4];
        #pragma unroll
        for (int cf = 0; cf < 32; ++cf) {
            f16x4 v0 = *(const f16x4*)&Vt[cf * 16 + li][gi * 4];
            f16x4 v1 = *(const f16x4*)&Vt[cf * 16 + li][16 + gi * 4];
            oacc[cf] = MFMA16(pa0, v0, oacc[cf]);
            oacc[cf] = MFMA16(pa1, v1, oacc[cf]);
        }
        __syncthreads();
    }

    // epilogue: unnormalized O partial + (m,l) stats
    const size_t rowb = (size_t)(jh * 4 + b) * NPIX;
    #pragma unroll
    for (int cf = 0; cf < 32; ++cf)
        #pragma unroll
        for (int r = 0; r < 4; ++r)
            opart[(rowb + i0 + gi * 4 + r) * 512 + cf * 16 + li] =
                (_Float16)oacc[cf][r];
    if (li == 0) {
        #pragma unroll
        for (int r = 0; r < 4; ++r) {
            const size_t idx = (rowb + i0 + gi * 4 + r) * 2;
            stats[idx]     = m_run[r];
            stats[idx + 1] = l_run[r];
        }
    }
}

// ---------------------------------------------------------------------------
// Combine j-half partials, normalize, transpose [i][c] -> out[b][c][i].
// ---------------------------------------------------------------------------
__global__ __launch_bounds__(256) void combine_kernel(
    const _Float16* __restrict__ opart, const float* __restrict__ stats,
    float* __restrict__ out)
{
    const int b  = blockIdx.z;
    const int c0 = blockIdx.y * 64;
    const int i0 = blockIdx.x * 64;
    const int t  = threadIdx.x;

    __shared__ float Lt[64][68];  // [c][i] transposed tile

    {
        const int il = t >> 2, cb = (t & 3) * 16;
        const int i = i0 + il;
        const size_t r0 = ((size_t)b * NPIX + i) * 2;
        const size_t r1 = ((size_t)(4 + b) * NPIX + i) * 2;
        const float m0 = stats[r0], l0 = stats[r0 + 1];
        const float m1 = stats[r1], l1 = stats[r1 + 1];
        const float M  = fmaxf(m0, m1);
        const float w0 = __expf(m0 - M), w1 = __expf(m1 - M);
        const float inv = 1.0f / (l0 * w0 + l1 * w1);
        const _Float16* p0 = opart + ((size_t)b * NPIX + i) * 512 + c0 + cb;
        const _Float16* p1 = opart + ((size_t)(4 + b) * NPIX + i) * 512 + c0 + cb;
        const f16x8 a0 = *(const f16x8*)p0;
        const f16x8 a1 = *(const f16x8*)(p0 + 8);
        const f16x8 b0 = *(const f16x8*)p1;
        const f16x8 b1 = *(const f16x8*)(p1 + 8);
        #pragma unroll
        for (int e = 0; e < 8; ++e) {
            Lt[cb + e][il]     = ((float)a0[e] * w0 + (float)b0[e] * w1) * inv;
            Lt[cb + 8 + e][il] = ((float)a1[e] * w0 + (float)b1[e] * w1) * inv;
        }
    }
    __syncthreads();
    {
        const int cl = t >> 2, ib = (t & 3) * 16;
        float* dst = out + ((size_t)b * CIN + c0 + cl) * NPIX + i0 + ib;
        #pragma unroll
        for (int q = 0; q < 4; ++q) {
            float4 vv;
            vv.x = Lt[cl][ib + q * 4 + 0];
            vv.y = Lt[cl][ib + q * 4 + 1];
            vv.z = Lt[cl][ib + q * 4 + 2];
            vv.w = Lt[cl][ib + q * 4 + 3];
            *(float4*)(dst + q * 4) = vv;
        }
    }
}

// ---------------------------------------------------------------------------
extern "C" void kernel_launch(void* const* d_in, const int* in_sizes, int n_in,
                              void* d_out, int out_size, void* d_ws,
                              size_t ws_size, hipStream_t stream)
{
    const float* x   = (const float*)d_in[0];
    const float* f_w = (const float*)d_in[1];
    const float* f_b = (const float*)d_in[2];
    const float* g_w = (const float*)d_in[3];
    const float* g_b = (const float*)d_in[4];
    const float* h_w = (const float*)d_in[5];
    const float* h_b = (const float*)d_in[6];
    float* out = (float*)d_out;

    _Float16* qw = (_Float16*)d_ws;
    _Float16* kw = qw + (size_t)4 * NPIX * 256;
    _Float16* vw = kw + (size_t)4 * NPIX * 256;
    _Float16* op = vw + (size_t)4 * CIN * NPIX;
    float* stats = (float*)(op + (size_t)2 * 4 * NPIX * 512);

    proj_kernel<<<dim3(64, 16, 4), 256, 0, stream>>>(
        x, f_w, f_b, g_w, g_b, h_w, h_b, qw, kw, vw);
    attn_kernel<<<dim3(32, 2, 4), 512, 0, stream>>>(qw, kw, vw, op, stats);
    combine_kernel<<<dim3(64, 8, 4), 256, 0, stream>>>(op, stats, out);
}